// Round 14
// baseline (311.451 us; speedup 1.0000x reference)
//
#include <hip/hip_runtime.h>
#include <hip/hip_bf16.h>

#define NN 50000
#define NE 800000
#define D 128
#define NL 3
#define G3 384

typedef __attribute__((ext_vector_type(4))) float f32x4;
typedef __attribute__((ext_vector_type(2))) float f32x2;
typedef _Float16 f16;
typedef __attribute__((ext_vector_type(8))) _Float16 f16x8;
typedef __attribute__((ext_vector_type(2))) _Float16 f16x2;

// ---------------------------------------------------------------------------
__global__ void detect_i64_kernel(const int* __restrict__ ei, int* __restrict__ flag) {
    __shared__ int any_nz;
    if (threadIdx.x == 0) any_nz = 0;
    __syncthreads();
    int v = ei[threadIdx.x * 2 + 1];
    if (v != 0) atomicOr(&any_nz, 1);
    __syncthreads();
    if (threadIdx.x == 0) *flag = (any_nz == 0) ? 1 : 0;  // 1 => int64
}

// ---------------------------------------------------------------------------
// CSR build: histogram (dst-only load, packed dst|rank) -> 3-phase scan ->
// atomic-free fill (src-only load).
#define HBLK ((NE / 4 + 255) / 256)
__global__ void hist_kernel(const int* __restrict__ ei, const int* __restrict__ flag,
                            int* __restrict__ counts, unsigned* __restrict__ dstrank) {
    const int fl = *flag;
    int base = blockIdx.x * blockDim.x + threadIdx.x;
    const int stride = HBLK * 256;
#pragma unroll
    for (int k = 0; k < 4; ++k) {
        int e = base + k * stride;
        if (e >= NE) continue;
        int dst = fl ? ei[2LL * (NE + e)] : ei[NE + e];
        unsigned r = (unsigned)atomicAdd(counts + dst, 1);
        dstrank[e] = (unsigned)dst | (r << 16);  // dst < 65536, rank < 65536
    }
}

#define SBLK 256
#define NSB ((NN + SBLK - 1) / SBLK)  // 196

__global__ __launch_bounds__(SBLK) void scan_reduce_kernel(const int* __restrict__ counts,
                                                           int* __restrict__ block_sums) {
    __shared__ int lds[SBLK];
    int i = blockIdx.x * SBLK + threadIdx.x;
    lds[threadIdx.x] = (i < NN) ? counts[i] : 0;
    __syncthreads();
    for (int off = SBLK / 2; off > 0; off >>= 1) {
        if (threadIdx.x < off) lds[threadIdx.x] += lds[threadIdx.x + off];
        __syncthreads();
    }
    if (threadIdx.x == 0) block_sums[blockIdx.x] = lds[0];
}

__global__ __launch_bounds__(256) void scan_offsets_kernel(const int* __restrict__ block_sums,
                                                           int* __restrict__ block_off,
                                                           int* __restrict__ row_start) {
    __shared__ int lds[256];
    int t = threadIdx.x;
    int v = (t < NSB) ? block_sums[t] : 0;
    lds[t] = v;
    __syncthreads();
    for (int off = 1; off < 256; off <<= 1) {
        int x = (t >= off) ? lds[t - off] : 0;
        __syncthreads();
        lds[t] += x;
        __syncthreads();
    }
    if (t < NSB) block_off[t] = lds[t] - v;  // exclusive
    if (t == 255) row_start[NN] = lds[255];  // total = NE
}

__global__ __launch_bounds__(SBLK) void scan_final_kernel(const int* __restrict__ counts,
                                                          const int* __restrict__ block_off,
                                                          int* __restrict__ row_start) {
    __shared__ int lds[SBLK];
    int i = blockIdx.x * SBLK + threadIdx.x;
    int v = (i < NN) ? counts[i] : 0;
    lds[threadIdx.x] = v;
    __syncthreads();
    for (int off = 1; off < SBLK; off <<= 1) {
        int x = (threadIdx.x >= off) ? lds[threadIdx.x - off] : 0;
        __syncthreads();
        lds[threadIdx.x] += x;
        __syncthreads();
    }
    if (i < NN) row_start[i] = block_off[blockIdx.x] + lds[threadIdx.x] - v;
}

__global__ void fill_kernel(const int* __restrict__ ei, const int* __restrict__ flag,
                            const int* __restrict__ row_start,
                            const unsigned* __restrict__ dstrank,
                            unsigned short* __restrict__ csr16) {
    const int fl = *flag;
    int base = blockIdx.x * blockDim.x + threadIdx.x;
    const int stride = HBLK * 256;
#pragma unroll
    for (int k = 0; k < 4; ++k) {
        int e = base + k * stride;
        if (e >= NE) continue;
        int src = fl ? ei[2LL * e] : ei[e];
        unsigned dr = dstrank[e];
        csr16[row_start[dr & 0xFFFF] + (int)(dr >> 16)] = (unsigned short)src;
    }
}

// ---------------------------------------------------------------------------
__global__ void init_h_kernel(const float* __restrict__ z, f16* __restrict__ h) {
    int i = blockIdx.x * blockDim.x + threadIdx.x;
    if (i * 2 >= NN * D) return;
    f32x2 v = *(const f32x2*)(z + i * 2);
    f16x2 o = {(f16)v[0], (f16)v[1]};
    *(f16x2*)(h + i * 2) = o;
}

__global__ void finalize_kernel(const f16* __restrict__ h, float* __restrict__ out) {
    int i = blockIdx.x * blockDim.x + threadIdx.x;
    if (i * 2 >= NN * D) return;
    f16x2 v = *(const f16x2*)(h + i * 2);
    f32x2 o = {(float)v[0], (float)v[1]};
    *(f32x2*)(out + i * 2) = o;
}

// ---------------------------------------------------------------------------
// Gather (round-11 proven): one wave per dst row, 4 eslots x 16 chunks,
// 2-deep edge ILP (slots eslot, eslot+4; step 8).
__global__ __launch_bounds__(256) void gather_kernel(
    const f16* __restrict__ h, const int* __restrict__ row_start,
    const unsigned short* __restrict__ csr16, f16* __restrict__ agg) {
    int row = blockIdx.x * 4 + (threadIdx.x >> 6);
    if (row >= NN) return;
    int lane = threadIdx.x & 63;
    int eslot = lane >> 4;       // 0..3
    int c0 = (lane & 15) * 8;    // col base (8 f16 = 16 B)
    int beg = row_start[row], end = row_start[row + 1];
    float acc[8] = {0.f, 0.f, 0.f, 0.f, 0.f, 0.f, 0.f, 0.f};
    float acc2[8] = {0.f, 0.f, 0.f, 0.f, 0.f, 0.f, 0.f, 0.f};
    int e = beg;
    for (; e + 7 < end; e += 8) {
        int s0 = (int)csr16[e + eslot];
        int s1 = (int)csr16[e + eslot + 4];
        f16x8 v0 = *(const f16x8*)(h + s0 * D + c0);
        f16x8 v1 = *(const f16x8*)(h + s1 * D + c0);
#pragma unroll
        for (int j = 0; j < 8; ++j) { acc[j] += (float)v0[j]; acc2[j] += (float)v1[j]; }
    }
    for (; e + eslot < end; e += 4) {
        int s = (int)csr16[e + eslot];
        f16x8 v = *(const f16x8*)(h + s * D + c0);
#pragma unroll
        for (int j = 0; j < 8; ++j) acc[j] += (float)v[j];
    }
#pragma unroll
    for (int j = 0; j < 8; ++j) {
        acc[j] += acc2[j];
        acc[j] += __shfl_xor(acc[j], 16, 64);
        acc[j] += __shfl_xor(acc[j], 32, 64);
    }
    if (lane < 16) {
        f16x8 o;
#pragma unroll
        for (int j = 0; j < 8; ++j) o[j] = (f16)acc[j];
        *(f16x8*)(agg + row * D + c0) = o;
    }
}

// ---------------------------------------------------------------------------
// WcT[l][g][c] = sum_j weight[l][c][j] * w_ih[g][j] (fp16); whh fp16.
__global__ void precompute_weights(const float* __restrict__ weight,
                                   const float* __restrict__ w_ih,
                                   const float* __restrict__ w_hh,
                                   f16* __restrict__ wct, f16* __restrict__ whh) {
    int l = blockIdx.x / G3;
    int g = blockIdx.x % G3;
    int c = threadIdx.x;  // 0..127
    __shared__ float wih_row[D];
    wih_row[c] = w_ih[g * D + c];
    __syncthreads();
    const float* wrow = weight + ((long long)l * D + c) * D;
    float acc = 0.f;
#pragma unroll 8
    for (int j = 0; j < D; ++j) acc += wrow[j] * wih_row[j];
    wct[((long long)l * G3 + g) * D + c] = (f16)acc;
    if (l == 0) whh[g * D + c] = (f16)w_hh[g * D + c];
}

// ---------------------------------------------------------------------------
// Fused GRU with LDS-staged weights. Block = 16 waves x 16 rows = 256 rows
// (1024 thr); NDT=2 d-tiles single-staged upfront (48KB, XOR-swizzled), one
// barrier, both compute phases back-to-back. 2 blocks/CU = 32 waves/CU cap;
// weight staging amortized over 2x rows vs the 512-thr version.
// Swizzle involution (16B units within a 16x256B panel): unit' = unit^(row&7).
#define TMG 256
#define NDT 2
#define GRUTHR 1024
#define MFMA_F16 __builtin_amdgcn_mfma_f32_16x16x32_f16
__global__ __launch_bounds__(GRUTHR) void gru_fused_kernel(
    const f16* __restrict__ agg, const f16* __restrict__ hin, f16* __restrict__ hout,
    const f16* __restrict__ wct, const f16* __restrict__ whh,
    const float* __restrict__ b_ih, const float* __restrict__ b_hh,
    float* __restrict__ out_f32) {
    __shared__ char wlds[NDT * 6 * 4096];
    const int tid = threadIdx.x;
    const int lane = tid & 63;
    const int wv = tid >> 6;   // 0..15
    const int fr = lane & 15;
    const int kg = lane >> 4;
    const int m0 = blockIdx.x * TMG;
    const int dt0 = blockIdx.y * NDT;

    int arow = m0 + wv * 16 + fr;
    int arc = arow < NN ? arow : NN - 1;
    const int abase = arc * D;

    f16x8 fa[4], fh[4];
#pragma unroll
    for (int ks = 0; ks < 4; ++ks) {
        int k0 = ks * 32 + kg * 8;
        fa[ks] = *(const f16x8*)(agg + abase + k0);
        fh[ks] = *(const f16x8*)(hin + abase + k0);
    }

    // Stage NDT*6 panels = 3072 16B units with 1024 threads: 3 units each.
#pragma unroll
    for (int p6 = 0; p6 < NDT * 6 * 256 / GRUTHR; ++p6) {
        int unit = tid + p6 * GRUTHR;
        int dpanel = unit >> 8;  // 0..11
        int dti = dpanel / 6;
        int panel = dpanel % 6;
        int u = unit & 255;
        int sr = u >> 4;
        int sc = (u & 15) * 8;
        int gr = (dt0 + dti) * 16;
        const f16* srcp = (panel < 3)
                              ? wct + (panel * 128 + gr + sr) * D + sc
                              : whh + ((panel - 3) * 128 + gr + sr) * D + sc;
        int wb = ((u * 16) ^ ((sr & 7) << 4));
        *(f16x8*)(wlds + dpanel * 4096 + wb) = *(const f16x8*)srcp;
    }
    __syncthreads();

#pragma unroll
    for (int dti = 0; dti < NDT; ++dti) {
        const int gr = (dt0 + dti) * 16;
        const char* wb0 = wlds + dti * 6 * 4096;
        f32x4 a_ir = {0, 0, 0, 0}, a_iz = {0, 0, 0, 0}, a_in = {0, 0, 0, 0};
        f32x4 a_hr = {0, 0, 0, 0}, a_hz = {0, 0, 0, 0}, a_hn = {0, 0, 0, 0};
#pragma unroll
        for (int ks = 0; ks < 4; ++ks) {
            const int kb = fr * 256 + (((ks * 4 + kg) ^ (fr & 7)) << 4);
            f16x8 bir = *(const f16x8*)(wb0 + 0 * 4096 + kb);
            f16x8 biz = *(const f16x8*)(wb0 + 1 * 4096 + kb);
            f16x8 bin = *(const f16x8*)(wb0 + 2 * 4096 + kb);
            f16x8 bhr = *(const f16x8*)(wb0 + 3 * 4096 + kb);
            f16x8 bhz = *(const f16x8*)(wb0 + 4 * 4096 + kb);
            f16x8 bhn = *(const f16x8*)(wb0 + 5 * 4096 + kb);
            a_ir = MFMA_F16(fa[ks], bir, a_ir, 0, 0, 0);
            a_iz = MFMA_F16(fa[ks], biz, a_iz, 0, 0, 0);
            a_in = MFMA_F16(fa[ks], bin, a_in, 0, 0, 0);
            a_hr = MFMA_F16(fh[ks], bhr, a_hr, 0, 0, 0);
            a_hz = MFMA_F16(fh[ks], bhz, a_hz, 0, 0, 0);
            a_hn = MFMA_F16(fh[ks], bhn, a_hn, 0, 0, 0);
        }
        const int d = gr + fr;
        float bir_ = b_ih[d], biz_ = b_ih[128 + d], bin_ = b_ih[256 + d];
        float bhr_ = b_hh[d], bhz_ = b_hh[128 + d], bhn_ = b_hh[256 + d];
#pragma unroll
        for (int j = 0; j < 4; ++j) {
            int row = m0 + wv * 16 + kg * 4 + j;
            if (row >= NN) continue;
            float ir = a_ir[j] + bir_, iz = a_iz[j] + biz_, in_ = a_in[j] + bin_;
            float hr = a_hr[j] + bhr_, hz = a_hz[j] + bhz_, hn = a_hn[j] + bhn_;
            float r = 1.f / (1.f + __expf(-(ir + hr)));
            float zz = 1.f / (1.f + __expf(-(iz + hz)));
            float e2 = __expf(2.f * (in_ + r * hn));
            float nn = 1.f - 2.f / (e2 + 1.f);  // tanh
            int off = row * D + d;
            float hold = (float)hin[off];
            float hnew = (1.f - zz) * nn + zz * hold;
            if (out_f32)
                out_f32[off] = hnew;
            else
                hout[off] = (f16)hnew;
        }
    }
}

// Fallback (no ping-pong room): full-D per block, in-place safe, 256 thr.
__global__ __launch_bounds__(256) void gru_fused_fallback(
    const f16* __restrict__ agg, const f16* __restrict__ hin, f16* __restrict__ hout,
    const f16* __restrict__ wct, const f16* __restrict__ whh,
    const float* __restrict__ b_ih, const float* __restrict__ b_hh) {
    const int tid = threadIdx.x;
    const int lane = tid & 63;
    const int wv = tid >> 6;
    const int fr = lane & 15;
    const int kg = lane >> 4;
    const int m0 = blockIdx.x * 64;
    int arow = m0 + wv * 16 + fr;
    int arc = arow < NN ? arow : NN - 1;
    const int abase = arc * D;
    f16x8 fa[4], fh[4];
#pragma unroll
    for (int ks = 0; ks < 4; ++ks) {
        int k0 = ks * 32 + kg * 8;
        fa[ks] = *(const f16x8*)(agg + abase + k0);
        fh[ks] = *(const f16x8*)(hin + abase + k0);
    }
#pragma unroll 1
    for (int dt = 0; dt < 8; ++dt) {
        const int g = dt * 16 + fr;
        f32x4 a_ir = {0, 0, 0, 0}, a_iz = {0, 0, 0, 0}, a_in = {0, 0, 0, 0};
        f32x4 a_hr = {0, 0, 0, 0}, a_hz = {0, 0, 0, 0}, a_hn = {0, 0, 0, 0};
#pragma unroll
        for (int ks = 0; ks < 4; ++ks) {
            int k0 = ks * 32 + kg * 8;
            f16x8 bir = *(const f16x8*)(wct + (g)*D + k0);
            f16x8 biz = *(const f16x8*)(wct + (128 + g) * D + k0);
            f16x8 bin = *(const f16x8*)(wct + (256 + g) * D + k0);
            f16x8 bhr = *(const f16x8*)(whh + (g)*D + k0);
            f16x8 bhz = *(const f16x8*)(whh + (128 + g) * D + k0);
            f16x8 bhn = *(const f16x8*)(whh + (256 + g) * D + k0);
            a_ir = MFMA_F16(fa[ks], bir, a_ir, 0, 0, 0);
            a_iz = MFMA_F16(fa[ks], biz, a_iz, 0, 0, 0);
            a_in = MFMA_F16(fa[ks], bin, a_in, 0, 0, 0);
            a_hr = MFMA_F16(fh[ks], bhr, a_hr, 0, 0, 0);
            a_hz = MFMA_F16(fh[ks], bhz, a_hz, 0, 0, 0);
            a_hn = MFMA_F16(fh[ks], bhn, a_hn, 0, 0, 0);
        }
        const int d = g;
        float bir_ = b_ih[d], biz_ = b_ih[128 + d], bin_ = b_ih[256 + d];
        float bhr_ = b_hh[d], bhz_ = b_hh[128 + d], bhn_ = b_hh[256 + d];
#pragma unroll
        for (int j = 0; j < 4; ++j) {
            int row = m0 + wv * 16 + kg * 4 + j;
            if (row >= NN) continue;
            float ir = a_ir[j] + bir_, iz = a_iz[j] + biz_, in_ = a_in[j] + bin_;
            float hr = a_hr[j] + bhr_, hz = a_hz[j] + bhz_, hn = a_hn[j] + bhn_;
            float r = 1.f / (1.f + __expf(-(ir + hr)));
            float zz = 1.f / (1.f + __expf(-(iz + hz)));
            float e2 = __expf(2.f * (in_ + r * hn));
            float nn = 1.f - 2.f / (e2 + 1.f);
            int off = row * D + d;
            float hold = (float)hin[off];
            hout[off] = (f16)((1.f - zz) * nn + zz * hold);
        }
    }
}

// ---------------------------------------------------------------------------
extern "C" void kernel_launch(void* const* d_in, const int* in_sizes, int n_in,
                              void* d_out, int out_size, void* d_ws, size_t ws_size,
                              hipStream_t stream) {
    const float* z = (const float*)d_in[0];
    const int* ei = (const int*)d_in[1];
    const float* weight = (const float*)d_in[2];
    const float* w_ih = (const float*)d_in[3];
    const float* w_hh = (const float*)d_in[4];
    const float* b_ih = (const float*)d_in[5];
    const float* b_hh = (const float*)d_in[6];
    float* out = (float*)d_out;

    char* ws = (char*)d_ws;
    size_t off = 0;
    f16* wct = (f16*)(ws + off); off += 294912;
    f16* whh = (f16*)(ws + off); off += 98304;
    int* flag       = (int*)(ws + off); off += 256;
    int* counts     = (int*)(ws + off); off += (size_t)NN * 4;
    int* row_start  = (int*)(ws + off); off += (size_t)(NN + 16) * 4;
    int* block_sums = (int*)(ws + off); off += (size_t)NSB * 4;
    int* block_off  = (int*)(ws + off); off += (size_t)NSB * 4;
    unsigned* dstrank = (unsigned*)(ws + off); off += (size_t)NE * 4;
    unsigned short* csr16 = (unsigned short*)(ws + off); off += (size_t)NE * 2;
    f16* agg  = (f16*)(ws + off); off += (size_t)NN * D * 2;
    f16* hA   = (f16*)(ws + off); off += (size_t)NN * D * 2;
    f16* hB   = (f16*)(ws + off); off += (size_t)NN * D * 2;
    const bool split = (ws_size >= off);  // room for ping-pong buffer?

    detect_i64_kernel<<<1, 256, 0, stream>>>(ei, flag);
    hipMemsetAsync(counts, 0, (size_t)NN * 4, stream);
    hist_kernel<<<HBLK, 256, 0, stream>>>(ei, flag, counts, dstrank);
    scan_reduce_kernel<<<NSB, SBLK, 0, stream>>>(counts, block_sums);
    scan_offsets_kernel<<<1, 256, 0, stream>>>(block_sums, block_off, row_start);
    scan_final_kernel<<<NSB, SBLK, 0, stream>>>(counts, block_off, row_start);
    fill_kernel<<<HBLK, 256, 0, stream>>>(ei, flag, row_start, dstrank, csr16);
    precompute_weights<<<NL * G3, 128, 0, stream>>>(weight, w_ih, w_hh, wct, whh);
    const int npair = NN * D / 2;
    init_h_kernel<<<(npair + 255) / 256, 256, 0, stream>>>(z, hA);

    if (split) {
        const dim3 gg((NN + TMG - 1) / TMG, 8 / NDT);
        const f16* cin = hA;
        for (int l = 0; l < NL; ++l) {
            gather_kernel<<<(NN + 3) / 4, 256, 0, stream>>>(cin, row_start, csr16, agg);
            f16* cout = (cin == hA) ? hB : hA;
            long long woff = (long long)l * G3 * D;
            float* last_out = (l == NL - 1) ? out : nullptr;
            gru_fused_kernel<<<gg, GRUTHR, 0, stream>>>(agg, cin, cout, wct + woff, whh,
                                                        b_ih, b_hh, last_out);
            cin = cout;
        }
    } else {
        // agg lives in d_out (f16 12.8MB < 25.6MB); finalize overwrites after.
        f16* aggo = (f16*)d_out;
        for (int l = 0; l < NL; ++l) {
            gather_kernel<<<(NN + 3) / 4, 256, 0, stream>>>(hA, row_start, csr16, aggo);
            long long woff = (long long)l * G3 * D;
            gru_fused_fallback<<<(NN + 63) / 64, 256, 0, stream>>>(
                aggo, hA, hA, wct + woff, whh, b_ih, b_hh);
        }
        finalize_kernel<<<(npair + 255) / 256, 256, 0, stream>>>(hA, out);
    }
}

// Round 15
// 298.738 us; speedup vs baseline: 1.0426x; 1.0426x over previous
//
#include <hip/hip_runtime.h>
#include <hip/hip_bf16.h>

#define NN 50000
#define NE 800000
#define D 128
#define NL 3
#define G3 384

typedef __attribute__((ext_vector_type(4))) float f32x4;
typedef __attribute__((ext_vector_type(2))) float f32x2;
typedef _Float16 f16;
typedef __attribute__((ext_vector_type(8))) _Float16 f16x8;
typedef __attribute__((ext_vector_type(2))) _Float16 f16x2;

// ---------------------------------------------------------------------------
__global__ void detect_i64_kernel(const int* __restrict__ ei, int* __restrict__ flag) {
    __shared__ int any_nz;
    if (threadIdx.x == 0) any_nz = 0;
    __syncthreads();
    int v = ei[threadIdx.x * 2 + 1];
    if (v != 0) atomicOr(&any_nz, 1);
    __syncthreads();
    if (threadIdx.x == 0) *flag = (any_nz == 0) ? 1 : 0;  // 1 => int64
}

// ---------------------------------------------------------------------------
// CSR build: histogram (1 edge/thread for max TLP; dst-only load; packed
// dst|rank<<16) -> 3-phase scan -> atomic-free ILP4 fill (src-only load).
__global__ void hist_kernel(const int* __restrict__ ei, const int* __restrict__ flag,
                            int* __restrict__ counts, unsigned* __restrict__ dstrank) {
    int e = blockIdx.x * blockDim.x + threadIdx.x;
    if (e >= NE) return;
    int dst = (*flag) ? ei[2LL * (NE + e)] : ei[NE + e];
    unsigned r = (unsigned)atomicAdd(counts + dst, 1);
    dstrank[e] = (unsigned)dst | (r << 16);  // dst < 65536, rank < 65536
}

#define SBLK 256
#define NSB ((NN + SBLK - 1) / SBLK)  // 196
#define FBLK ((NE / 4 + 255) / 256)

__global__ __launch_bounds__(SBLK) void scan_reduce_kernel(const int* __restrict__ counts,
                                                           int* __restrict__ block_sums) {
    __shared__ int lds[SBLK];
    int i = blockIdx.x * SBLK + threadIdx.x;
    lds[threadIdx.x] = (i < NN) ? counts[i] : 0;
    __syncthreads();
    for (int off = SBLK / 2; off > 0; off >>= 1) {
        if (threadIdx.x < off) lds[threadIdx.x] += lds[threadIdx.x + off];
        __syncthreads();
    }
    if (threadIdx.x == 0) block_sums[blockIdx.x] = lds[0];
}

__global__ __launch_bounds__(256) void scan_offsets_kernel(const int* __restrict__ block_sums,
                                                           int* __restrict__ block_off,
                                                           int* __restrict__ row_start) {
    __shared__ int lds[256];
    int t = threadIdx.x;
    int v = (t < NSB) ? block_sums[t] : 0;
    lds[t] = v;
    __syncthreads();
    for (int off = 1; off < 256; off <<= 1) {
        int x = (t >= off) ? lds[t - off] : 0;
        __syncthreads();
        lds[t] += x;
        __syncthreads();
    }
    if (t < NSB) block_off[t] = lds[t] - v;  // exclusive
    if (t == 255) row_start[NN] = lds[255];  // total = NE
}

__global__ __launch_bounds__(SBLK) void scan_final_kernel(const int* __restrict__ counts,
                                                          const int* __restrict__ block_off,
                                                          int* __restrict__ row_start) {
    __shared__ int lds[SBLK];
    int i = blockIdx.x * SBLK + threadIdx.x;
    int v = (i < NN) ? counts[i] : 0;
    lds[threadIdx.x] = v;
    __syncthreads();
    for (int off = 1; off < SBLK; off <<= 1) {
        int x = (threadIdx.x >= off) ? lds[threadIdx.x - off] : 0;
        __syncthreads();
        lds[threadIdx.x] += x;
        __syncthreads();
    }
    if (i < NN) row_start[i] = block_off[blockIdx.x] + lds[threadIdx.x] - v;
}

__global__ void fill_kernel(const int* __restrict__ ei, const int* __restrict__ flag,
                            const int* __restrict__ row_start,
                            const unsigned* __restrict__ dstrank,
                            unsigned short* __restrict__ csr16) {
    const int fl = *flag;
    int base = blockIdx.x * blockDim.x + threadIdx.x;
    const int stride = FBLK * 256;
#pragma unroll
    for (int k = 0; k < 4; ++k) {
        int e = base + k * stride;
        if (e >= NE) continue;
        int src = fl ? ei[2LL * e] : ei[e];
        unsigned dr = dstrank[e];
        csr16[row_start[dr & 0xFFFF] + (int)(dr >> 16)] = (unsigned short)src;
    }
}

// ---------------------------------------------------------------------------
__global__ void init_h_kernel(const float* __restrict__ z, f16* __restrict__ h) {
    int i = blockIdx.x * blockDim.x + threadIdx.x;
    if (i * 2 >= NN * D) return;
    f32x2 v = *(const f32x2*)(z + i * 2);
    f16x2 o = {(f16)v[0], (f16)v[1]};
    *(f16x2*)(h + i * 2) = o;
}

__global__ void finalize_kernel(const f16* __restrict__ h, float* __restrict__ out) {
    int i = blockIdx.x * blockDim.x + threadIdx.x;
    if (i * 2 >= NN * D) return;
    f16x2 v = *(const f16x2*)(h + i * 2);
    f32x2 o = {(float)v[0], (float)v[1]};
    *(f32x2*)(out + i * 2) = o;
}

// ---------------------------------------------------------------------------
// Gather (round-11 proven): one wave per dst row, 4 eslots x 16 chunks,
// 2-deep edge ILP (slots eslot, eslot+4; step 8).
__global__ __launch_bounds__(256) void gather_kernel(
    const f16* __restrict__ h, const int* __restrict__ row_start,
    const unsigned short* __restrict__ csr16, f16* __restrict__ agg) {
    int row = blockIdx.x * 4 + (threadIdx.x >> 6);
    if (row >= NN) return;
    int lane = threadIdx.x & 63;
    int eslot = lane >> 4;       // 0..3
    int c0 = (lane & 15) * 8;    // col base (8 f16 = 16 B)
    int beg = row_start[row], end = row_start[row + 1];
    float acc[8] = {0.f, 0.f, 0.f, 0.f, 0.f, 0.f, 0.f, 0.f};
    float acc2[8] = {0.f, 0.f, 0.f, 0.f, 0.f, 0.f, 0.f, 0.f};
    int e = beg;
    for (; e + 7 < end; e += 8) {
        int s0 = (int)csr16[e + eslot];
        int s1 = (int)csr16[e + eslot + 4];
        f16x8 v0 = *(const f16x8*)(h + s0 * D + c0);
        f16x8 v1 = *(const f16x8*)(h + s1 * D + c0);
#pragma unroll
        for (int j = 0; j < 8; ++j) { acc[j] += (float)v0[j]; acc2[j] += (float)v1[j]; }
    }
    for (; e + eslot < end; e += 4) {
        int s = (int)csr16[e + eslot];
        f16x8 v = *(const f16x8*)(h + s * D + c0);
#pragma unroll
        for (int j = 0; j < 8; ++j) acc[j] += (float)v[j];
    }
#pragma unroll
    for (int j = 0; j < 8; ++j) {
        acc[j] += acc2[j];
        acc[j] += __shfl_xor(acc[j], 16, 64);
        acc[j] += __shfl_xor(acc[j], 32, 64);
    }
    if (lane < 16) {
        f16x8 o;
#pragma unroll
        for (int j = 0; j < 8; ++j) o[j] = (f16)acc[j];
        *(f16x8*)(agg + row * D + c0) = o;
    }
}

// ---------------------------------------------------------------------------
// WcT[l][g][c] = sum_j weight[l][c][j] * w_ih[g][j] (fp16); whh fp16.
__global__ void precompute_weights(const float* __restrict__ weight,
                                   const float* __restrict__ w_ih,
                                   const float* __restrict__ w_hh,
                                   f16* __restrict__ wct, f16* __restrict__ whh) {
    int l = blockIdx.x / G3;
    int g = blockIdx.x % G3;
    int c = threadIdx.x;  // 0..127
    __shared__ float wih_row[D];
    wih_row[c] = w_ih[g * D + c];
    __syncthreads();
    const float* wrow = weight + ((long long)l * D + c) * D;
    float acc = 0.f;
#pragma unroll 8
    for (int j = 0; j < D; ++j) acc += wrow[j] * wih_row[j];
    wct[((long long)l * G3 + g) * D + c] = (f16)acc;
    if (l == 0) whh[g * D + c] = (f16)w_hh[g * D + c];
}

// ---------------------------------------------------------------------------
// Fused GRU with LDS-staged weights (round-11 proven best config).
// Block = 8 waves x 16 rows = 128 rows (512 thr); NDT=2 d-tiles single-staged
// upfront (48KB, XOR-swizzled), ONE barrier, both compute phases back-to-back.
// Swizzle involution (16B units within a 16x256B panel): unit' = unit^(row&7).
#define TMG 128
#define NDT 2
#define MFMA_F16 __builtin_amdgcn_mfma_f32_16x16x32_f16
__global__ __launch_bounds__(512) void gru_fused_kernel(
    const f16* __restrict__ agg, const f16* __restrict__ hin, f16* __restrict__ hout,
    const f16* __restrict__ wct, const f16* __restrict__ whh,
    const float* __restrict__ b_ih, const float* __restrict__ b_hh,
    float* __restrict__ out_f32) {
    __shared__ char wlds[NDT * 6 * 4096];
    const int tid = threadIdx.x;
    const int lane = tid & 63;
    const int wv = tid >> 6;   // 0..7
    const int fr = lane & 15;
    const int kg = lane >> 4;
    const int m0 = blockIdx.x * TMG;
    const int dt0 = blockIdx.y * NDT;

    int arow = m0 + wv * 16 + fr;
    int arc = arow < NN ? arow : NN - 1;
    const int abase = arc * D;

    f16x8 fa[4], fh[4];
#pragma unroll
    for (int ks = 0; ks < 4; ++ks) {
        int k0 = ks * 32 + kg * 8;
        fa[ks] = *(const f16x8*)(agg + abase + k0);
        fh[ks] = *(const f16x8*)(hin + abase + k0);
    }

#pragma unroll
    for (int p6 = 0; p6 < NDT * 3; ++p6) {
        int unit = tid + p6 * 512;
        int dpanel = unit >> 8;
        int dti = dpanel / 6;
        int panel = dpanel % 6;
        int u = unit & 255;
        int sr = u >> 4;
        int sc = (u & 15) * 8;
        int gr = (dt0 + dti) * 16;
        const f16* srcp = (panel < 3)
                              ? wct + (panel * 128 + gr + sr) * D + sc
                              : whh + ((panel - 3) * 128 + gr + sr) * D + sc;
        int wb = (u * 16) ^ ((sr & 7) << 4);
        *(f16x8*)(wlds + dpanel * 4096 + wb) = *(const f16x8*)srcp;
    }
    __syncthreads();

#pragma unroll
    for (int dti = 0; dti < NDT; ++dti) {
        const int gr = (dt0 + dti) * 16;
        const char* wb0 = wlds + dti * 6 * 4096;
        f32x4 a_ir = {0, 0, 0, 0}, a_iz = {0, 0, 0, 0}, a_in = {0, 0, 0, 0};
        f32x4 a_hr = {0, 0, 0, 0}, a_hz = {0, 0, 0, 0}, a_hn = {0, 0, 0, 0};
#pragma unroll
        for (int ks = 0; ks < 4; ++ks) {
            const int kb = fr * 256 + (((ks * 4 + kg) ^ (fr & 7)) << 4);
            f16x8 bir = *(const f16x8*)(wb0 + 0 * 4096 + kb);
            f16x8 biz = *(const f16x8*)(wb0 + 1 * 4096 + kb);
            f16x8 bin = *(const f16x8*)(wb0 + 2 * 4096 + kb);
            f16x8 bhr = *(const f16x8*)(wb0 + 3 * 4096 + kb);
            f16x8 bhz = *(const f16x8*)(wb0 + 4 * 4096 + kb);
            f16x8 bhn = *(const f16x8*)(wb0 + 5 * 4096 + kb);
            a_ir = MFMA_F16(fa[ks], bir, a_ir, 0, 0, 0);
            a_iz = MFMA_F16(fa[ks], biz, a_iz, 0, 0, 0);
            a_in = MFMA_F16(fa[ks], bin, a_in, 0, 0, 0);
            a_hr = MFMA_F16(fh[ks], bhr, a_hr, 0, 0, 0);
            a_hz = MFMA_F16(fh[ks], bhz, a_hz, 0, 0, 0);
            a_hn = MFMA_F16(fh[ks], bhn, a_hn, 0, 0, 0);
        }
        const int d = gr + fr;
        float bir_ = b_ih[d], biz_ = b_ih[128 + d], bin_ = b_ih[256 + d];
        float bhr_ = b_hh[d], bhz_ = b_hh[128 + d], bhn_ = b_hh[256 + d];
#pragma unroll
        for (int j = 0; j < 4; ++j) {
            int row = m0 + wv * 16 + kg * 4 + j;
            if (row >= NN) continue;
            float ir = a_ir[j] + bir_, iz = a_iz[j] + biz_, in_ = a_in[j] + bin_;
            float hr = a_hr[j] + bhr_, hz = a_hz[j] + bhz_, hn = a_hn[j] + bhn_;
            float r = 1.f / (1.f + __expf(-(ir + hr)));
            float zz = 1.f / (1.f + __expf(-(iz + hz)));
            float e2 = __expf(2.f * (in_ + r * hn));
            float nn = 1.f - 2.f / (e2 + 1.f);  // tanh
            int off = row * D + d;
            float hold = (float)hin[off];
            float hnew = (1.f - zz) * nn + zz * hold;
            if (out_f32)
                out_f32[off] = hnew;
            else
                hout[off] = (f16)hnew;
        }
    }
}

// Fallback (no ping-pong room): full-D per block, in-place safe, 256 thr.
__global__ __launch_bounds__(256) void gru_fused_fallback(
    const f16* __restrict__ agg, const f16* __restrict__ hin, f16* __restrict__ hout,
    const f16* __restrict__ wct, const f16* __restrict__ whh,
    const float* __restrict__ b_ih, const float* __restrict__ b_hh) {
    const int tid = threadIdx.x;
    const int lane = tid & 63;
    const int wv = tid >> 6;
    const int fr = lane & 15;
    const int kg = lane >> 4;
    const int m0 = blockIdx.x * 64;
    int arow = m0 + wv * 16 + fr;
    int arc = arow < NN ? arow : NN - 1;
    const int abase = arc * D;
    f16x8 fa[4], fh[4];
#pragma unroll
    for (int ks = 0; ks < 4; ++ks) {
        int k0 = ks * 32 + kg * 8;
        fa[ks] = *(const f16x8*)(agg + abase + k0);
        fh[ks] = *(const f16x8*)(hin + abase + k0);
    }
#pragma unroll 1
    for (int dt = 0; dt < 8; ++dt) {
        const int g = dt * 16 + fr;
        f32x4 a_ir = {0, 0, 0, 0}, a_iz = {0, 0, 0, 0}, a_in = {0, 0, 0, 0};
        f32x4 a_hr = {0, 0, 0, 0}, a_hz = {0, 0, 0, 0}, a_hn = {0, 0, 0, 0};
#pragma unroll
        for (int ks = 0; ks < 4; ++ks) {
            int k0 = ks * 32 + kg * 8;
            f16x8 bir = *(const f16x8*)(wct + (g)*D + k0);
            f16x8 biz = *(const f16x8*)(wct + (128 + g) * D + k0);
            f16x8 bin = *(const f16x8*)(wct + (256 + g) * D + k0);
            f16x8 bhr = *(const f16x8*)(whh + (g)*D + k0);
            f16x8 bhz = *(const f16x8*)(whh + (128 + g) * D + k0);
            f16x8 bhn = *(const f16x8*)(whh + (256 + g) * D + k0);
            a_ir = MFMA_F16(fa[ks], bir, a_ir, 0, 0, 0);
            a_iz = MFMA_F16(fa[ks], biz, a_iz, 0, 0, 0);
            a_in = MFMA_F16(fa[ks], bin, a_in, 0, 0, 0);
            a_hr = MFMA_F16(fh[ks], bhr, a_hr, 0, 0, 0);
            a_hz = MFMA_F16(fh[ks], bhz, a_hz, 0, 0, 0);
            a_hn = MFMA_F16(fh[ks], bhn, a_hn, 0, 0, 0);
        }
        const int d = g;
        float bir_ = b_ih[d], biz_ = b_ih[128 + d], bin_ = b_ih[256 + d];
        float bhr_ = b_hh[d], bhz_ = b_hh[128 + d], bhn_ = b_hh[256 + d];
#pragma unroll
        for (int j = 0; j < 4; ++j) {
            int row = m0 + wv * 16 + kg * 4 + j;
            if (row >= NN) continue;
            float ir = a_ir[j] + bir_, iz = a_iz[j] + biz_, in_ = a_in[j] + bin_;
            float hr = a_hr[j] + bhr_, hz = a_hz[j] + bhz_, hn = a_hn[j] + bhn_;
            float r = 1.f / (1.f + __expf(-(ir + hr)));
            float zz = 1.f / (1.f + __expf(-(iz + hz)));
            float e2 = __expf(2.f * (in_ + r * hn));
            float nn = 1.f - 2.f / (e2 + 1.f);
            int off = row * D + d;
            float hold = (float)hin[off];
            hout[off] = (f16)((1.f - zz) * nn + zz * hold);
        }
    }
}

// ---------------------------------------------------------------------------
extern "C" void kernel_launch(void* const* d_in, const int* in_sizes, int n_in,
                              void* d_out, int out_size, void* d_ws, size_t ws_size,
                              hipStream_t stream) {
    const float* z = (const float*)d_in[0];
    const int* ei = (const int*)d_in[1];
    const float* weight = (const float*)d_in[2];
    const float* w_ih = (const float*)d_in[3];
    const float* w_hh = (const float*)d_in[4];
    const float* b_ih = (const float*)d_in[5];
    const float* b_hh = (const float*)d_in[6];
    float* out = (float*)d_out;

    char* ws = (char*)d_ws;
    size_t off = 0;
    f16* wct = (f16*)(ws + off); off += 294912;
    f16* whh = (f16*)(ws + off); off += 98304;
    int* flag       = (int*)(ws + off); off += 256;
    int* counts     = (int*)(ws + off); off += (size_t)NN * 4;
    int* row_start  = (int*)(ws + off); off += (size_t)(NN + 16) * 4;
    int* block_sums = (int*)(ws + off); off += (size_t)NSB * 4;
    int* block_off  = (int*)(ws + off); off += (size_t)NSB * 4;
    unsigned* dstrank = (unsigned*)(ws + off); off += (size_t)NE * 4;
    unsigned short* csr16 = (unsigned short*)(ws + off); off += (size_t)NE * 2;
    f16* agg  = (f16*)(ws + off); off += (size_t)NN * D * 2;
    f16* hA   = (f16*)(ws + off); off += (size_t)NN * D * 2;
    f16* hB   = (f16*)(ws + off); off += (size_t)NN * D * 2;
    const bool split = (ws_size >= off);  // room for ping-pong buffer?

    detect_i64_kernel<<<1, 256, 0, stream>>>(ei, flag);
    hipMemsetAsync(counts, 0, (size_t)NN * 4, stream);
    hist_kernel<<<(NE + 255) / 256, 256, 0, stream>>>(ei, flag, counts, dstrank);
    scan_reduce_kernel<<<NSB, SBLK, 0, stream>>>(counts, block_sums);
    scan_offsets_kernel<<<1, 256, 0, stream>>>(block_sums, block_off, row_start);
    scan_final_kernel<<<NSB, SBLK, 0, stream>>>(counts, block_off, row_start);
    fill_kernel<<<FBLK, 256, 0, stream>>>(ei, flag, row_start, dstrank, csr16);
    precompute_weights<<<NL * G3, 128, 0, stream>>>(weight, w_ih, w_hh, wct, whh);
    const int npair = NN * D / 2;
    init_h_kernel<<<(npair + 255) / 256, 256, 0, stream>>>(z, hA);

    if (split) {
        const dim3 gg((NN + TMG - 1) / TMG, 8 / NDT);
        const f16* cin = hA;
        for (int l = 0; l < NL; ++l) {
            gather_kernel<<<(NN + 3) / 4, 256, 0, stream>>>(cin, row_start, csr16, agg);
            f16* cout = (cin == hA) ? hB : hA;
            long long woff = (long long)l * G3 * D;
            float* last_out = (l == NL - 1) ? out : nullptr;
            gru_fused_kernel<<<gg, 512, 0, stream>>>(agg, cin, cout, wct + woff, whh,
                                                     b_ih, b_hh, last_out);
            cin = cout;
        }
    } else {
        // agg lives in d_out (f16 12.8MB < 25.6MB); finalize overwrites after.
        f16* aggo = (f16*)d_out;
        for (int l = 0; l < NL; ++l) {
            gather_kernel<<<(NN + 3) / 4, 256, 0, stream>>>(hA, row_start, csr16, aggo);
            long long woff = (long long)l * G3 * D;
            gru_fused_fallback<<<(NN + 63) / 64, 256, 0, stream>>>(
                aggo, hA, hA, wct + woff, whh, b_ih, b_hh);
        }
        finalize_kernel<<<(npair + 255) / 256, 256, 0, stream>>>(hA, out);
    }
}